// Round 1
// 237.621 us; speedup vs baseline: 1.1409x; 1.1409x over previous
//
#include <hip/hip_runtime.h>
#include <hip/hip_fp16.h>

#define NN 50000      // nodes (fits in 16 bits: col packed as ushort)
#define NE 800000     // edges
#define DF 64         // features
#define MM 11         // (a,b) tuples
#define OUT_K 4       // DEPTH+1 output planes
#define PAD 16        // row slabs padded to multiple of PAD
#define SLAB_CAP (NE + (PAD - 1) * NN + 64)

__device__ __forceinline__ float bf2f(unsigned short u) {
    union { unsigned int i; float f; } v; v.i = ((unsigned int)u) << 16; return v.f;
}
__device__ __forceinline__ unsigned short f2bf(float f) {
    union { float f; unsigned int i; } v; v.f = f;
    unsigned int u = v.i + 0x7FFFu + ((v.i >> 16) & 1u);
    return (unsigned short)(u >> 16);
}

// ---------------- CSR build ----------------

// deg AND per-edge rank within its row (the atomic's old value — free sort key)
__global__ void k_deg(const int* __restrict__ row, int* __restrict__ deg,
                      unsigned short* __restrict__ rank) {
    int e = blockIdx.x * blockDim.x + threadIdx.x;
    if (e < NE) {
        int r = row[e];
        rank[e] = (unsigned short)atomicAdd(&deg[r], 1);
    }
}

// slab alloc: 1024-thread blocks, two-level (wave shfl + LDS) scan,
// ONE atomic per block (49 total). gamma parallelized over m on wave 0 of block 0.
__global__ __launch_bounds__(1024) void k_alloc(
        const int* __restrict__ deg, int* __restrict__ counter,
        int* __restrict__ rowstart, float* __restrict__ dinv,
        const float* __restrict__ alphas, const float* __restrict__ w,
        const float* __restrict__ a_arr, const float* __restrict__ b_arr,
        float* __restrict__ gamma) {
    __shared__ int wtot[16];
    __shared__ int blockbase;
    int i = blockIdx.x * 1024 + threadIdx.x;
    int wave = threadIdx.x >> 6;
    int lane = threadIdx.x & 63;

    int d = (i < NN) ? deg[i] : 0;
    int dp = (d + PAD - 1) & ~(PAD - 1);
    int v = dp;
    #pragma unroll
    for (int off = 1; off < 64; off <<= 1) {
        int t = __shfl_up(v, off, 64);
        if (lane >= off) v += t;
    }
    if (lane == 63) wtot[wave] = v;
    __syncthreads();
    if (wave == 0) {
        int t = (lane < 16) ? wtot[lane] : 0;
        #pragma unroll
        for (int off = 1; off < 16; off <<= 1) {
            int u = __shfl_up(t, off, 64);
            if (lane >= off) t += u;
        }
        if (lane == 15) blockbase = atomicAdd(counter, t);  // block total
        if (lane < 16) wtot[lane] = t;                      // inclusive scan
    }
    __syncthreads();
    int base = blockbase + (wave ? wtot[wave - 1] : 0);
    if (i < NN) {
        rowstart[i] = base + v - dp;
        dinv[i] = 1.0f / sqrtf((float)(d == 0 ? 1 : d));
    }

    // gamma[k][j] = sum_m w_m c_{k,m,j}: one m per lane, shuffle-reduce.
    if (blockIdx.x == 0 && wave == 0) {
        float g[OUT_K][OUT_K];
        #pragma unroll
        for (int k = 0; k < OUT_K; ++k)
            #pragma unroll
            for (int j = 0; j < OUT_K; ++j) g[k][j] = 0.f;
        if (lane < MM) {
            int m = lane;
            float a = a_arr[m], b = b_arr[m], wm = w[m];
            float c[OUT_K][OUT_K];
            #pragma unroll
            for (int k = 0; k < OUT_K; ++k)
                #pragma unroll
                for (int j = 0; j < OUT_K; ++j) c[k][j] = 0.f;
            c[0][0] = 1.f;
            float al0 = alphas[m];
            c[1][0] = al0 * 0.5f * (a - b);        // l=-1, r=1
            c[1][1] = al0 * 0.5f * (a + b + 2.f);
            #pragma unroll
            for (int L = 2; L <= 3; ++L) {
                float Lf = (float)L;
                float alL = alphas[(L - 1) * MM + m];
                float alm = alphas[(L - 2) * MM + m];
                float ab = a + b;
                float t2L = 2.f * Lf + ab;
                float coef_l = 2.f * Lf * (Lf + ab) * (t2L - 2.f);
                float inv = 1.f / coef_l;
                float t1 = alL * ((t2L - 1.f) * t2L * (t2L - 2.f)) * inv;
                float t2 = alL * ((t2L - 1.f) * (a * a - b * b)) * inv;
                float t3 = alL * alm * (2.f * (Lf - 1.f + a) * (Lf - 1.f + b) * t2L) * inv;
                #pragma unroll
                for (int j = 0; j < OUT_K; ++j) {
                    float ps = (j > 0) ? c[L - 1][j - 1] : 0.f;
                    c[L][j] = t1 * ps - t2 * c[L - 1][j] - t3 * c[L - 2][j];
                }
            }
            #pragma unroll
            for (int k = 0; k < OUT_K; ++k)
                #pragma unroll
                for (int j = 0; j < OUT_K; ++j) g[k][j] = wm * c[k][j];
        }
        #pragma unroll
        for (int k = 0; k < OUT_K; ++k)
            #pragma unroll
            for (int j = 0; j < OUT_K; ++j) {
                float s = g[k][j];
                #pragma unroll
                for (int off = 32; off >= 1; off >>= 1) s += __shfl_down(s, off, 64);
                if (lane == 0) gamma[k * OUT_K + j] = s;
            }
    }
}

// fill (atomic-free: pos = rowstart + precomputed rank) + vectorized bf16 cast of x
__global__ void k_fill_cast(const int* __restrict__ row, const int* __restrict__ col,
                            const float* __restrict__ ea, const float* __restrict__ dinv,
                            const int* __restrict__ rowstart,
                            const unsigned short* __restrict__ rank,
                            unsigned int* __restrict__ ecv,
                            const float* __restrict__ x, unsigned short* __restrict__ xb) {
    int t = blockIdx.x * blockDim.x + threadIdx.x;
    if (t < NE) {
        int r = row[t], c = col[t];
        int pos = rowstart[r] + (int)rank[t];
        float v = dinv[r] * ea[t] * dinv[c];
        unsigned short hb = __half_as_ushort(__float2half(v));
        ecv[pos] = (unsigned int)(unsigned short)c | ((unsigned int)hb << 16);
    } else {
        int j = t - NE;
        if (j < (NN * DF) / 8) {
            const float4* xf = (const float4*)x;
            float4 f0 = xf[2 * j];
            float4 f1 = xf[2 * j + 1];
            uint4 o;
            o.x = (unsigned int)f2bf(f0.x) | ((unsigned int)f2bf(f0.y) << 16);
            o.y = (unsigned int)f2bf(f0.z) | ((unsigned int)f2bf(f0.w) << 16);
            o.z = (unsigned int)f2bf(f1.x) | ((unsigned int)f2bf(f1.y) << 16);
            o.w = (unsigned int)f2bf(f1.z) | ((unsigned int)f2bf(f1.w) << 16);
            ((uint4*)xb)[j] = o;
        }
    }
}

// ---------------- SpMM: wave per row, lane = feature, PAD-wide batches, no tail ----
__device__ __forceinline__ float spmm_row(const unsigned int* __restrict__ ecv,
                                          int s, int n,
                                          const unsigned short* __restrict__ xin,
                                          int lane) {
    float acc = 0.f;
    for (int i = s; i < s + n; i += PAD) {
        unsigned int rec[PAD];
        #pragma unroll
        for (int j = 0; j < PAD; ++j) rec[j] = __builtin_nontemporal_load(&ecv[i + j]);
        unsigned short g[PAD];
        float vv[PAD];
        #pragma unroll
        for (int j = 0; j < PAD; ++j) {
            int c = (int)(rec[j] & 0xFFFFu);
            vv[j] = __half2float(__ushort_as_half((unsigned short)(rec[j] >> 16)));
            g[j] = xin[c * DF + lane];
        }
        #pragma unroll
        for (int j = 0; j < PAD; ++j) acc += vv[j] * bf2f(g[j]);
    }
    return acc;
}

__global__ __launch_bounds__(256) void k_spmm(
    const int* __restrict__ rowstart, const int* __restrict__ deg,
    const unsigned int* __restrict__ ecv, const unsigned short* __restrict__ xin,
    float* __restrict__ yout, unsigned short* __restrict__ bout) {
    int r = (blockIdx.x * blockDim.x + threadIdx.x) >> 6;
    int lane = threadIdx.x & 63;
    if (r >= NN) return;
    int s = rowstart[r];
    int n = (deg[r] + PAD - 1) & ~(PAD - 1);
    float acc = spmm_row(ecv, s, n, xin, lane);
    yout[r * DF + lane] = acc;
    bout[r * DF + lane] = f2bf(acc);
}

// third SpMM with the output combine fused (y3 never hits memory)
__global__ __launch_bounds__(256) void k_spmm_comb(
    const int* __restrict__ rowstart, const int* __restrict__ deg,
    const unsigned int* __restrict__ ecv, const unsigned short* __restrict__ xin,
    const float* __restrict__ x, const float* __restrict__ y1,
    const float* __restrict__ y2, const float* __restrict__ gamma,
    float* __restrict__ out) {
    int r = (blockIdx.x * blockDim.x + threadIdx.x) >> 6;
    int lane = threadIdx.x & 63;
    if (r >= NN) return;
    int s = rowstart[r];
    int n = (deg[r] + PAD - 1) & ~(PAD - 1);
    float v3 = spmm_row(ecv, s, n, xin, lane);
    int i = r * DF + lane;
    float v0 = x[i], v1 = y1[i], v2 = y2[i];
    float gm[OUT_K * OUT_K];
    #pragma unroll
    for (int t = 0; t < OUT_K * OUT_K; ++t) gm[t] = gamma[t];
    #pragma unroll
    for (int k = 0; k < OUT_K; ++k) {
        float o = gm[k * OUT_K + 0] * v0 + gm[k * OUT_K + 1] * v1 +
                  gm[k * OUT_K + 2] * v2 + gm[k * OUT_K + 3] * v3;
        out[(r * OUT_K + k) * DF + lane] = o;
    }
}

// ---------------- launch ----------------

extern "C" void kernel_launch(void* const* d_in, const int* in_sizes, int n_in,
                              void* d_out, int out_size, void* d_ws, size_t ws_size,
                              hipStream_t stream) {
    const float* x      = (const float*)d_in[0];
    const int*   ei     = (const int*)d_in[1];
    const float* ea     = (const float*)d_in[2];
    const float* alphas = (const float*)d_in[3];
    const float* w      = (const float*)d_in[4];
    const float* a_arr  = (const float*)d_in[5];
    const float* b_arr  = (const float*)d_in[6];
    float* out = (float*)d_out;
    const int* row = ei;
    const int* col = ei + NE;

    char* ws = (char*)d_ws;
    size_t off = 0;
    auto alloc = [&](size_t bytes) {
        void* p = ws + off;
        off = (off + bytes + 255) & ~(size_t)255;
        return p;
    };
    // deg/counter then ecv are contiguous so ONE memset zeroes all
    // (ecv pad slots must be 0: col=0, fp16 val=0).
    int* deg      = (int*)alloc((size_t)(NN + 1) * sizeof(int));
    int* counter  = deg + NN;
    unsigned int* ecv = (unsigned int*)alloc((size_t)SLAB_CAP * sizeof(unsigned int));
    size_t zero_end = off;
    int* rowstart = (int*)alloc((size_t)NN * sizeof(int));
    float* dinv   = (float*)alloc((size_t)NN * sizeof(float));
    unsigned short* rank = (unsigned short*)alloc((size_t)NE * sizeof(unsigned short));
    unsigned short* xb0 = (unsigned short*)alloc((size_t)NN * DF * sizeof(unsigned short));
    unsigned short* xb1 = (unsigned short*)alloc((size_t)NN * DF * sizeof(unsigned short));
    unsigned short* xb2 = (unsigned short*)alloc((size_t)NN * DF * sizeof(unsigned short));
    float* y1 = (float*)alloc((size_t)NN * DF * sizeof(float));
    float* y2 = (float*)alloc((size_t)NN * DF * sizeof(float));
    float* gamma = (float*)alloc((size_t)OUT_K * OUT_K * sizeof(float));

    (void)hipMemsetAsync(deg, 0, zero_end, stream);

    k_deg<<<(NE + 255) / 256, 256, 0, stream>>>(row, deg, rank);
    k_alloc<<<(NN + 1023) / 1024, 1024, 0, stream>>>(deg, counter, rowstart, dinv,
                                                     alphas, w, a_arr, b_arr, gamma);
    k_fill_cast<<<(NE + (NN * DF) / 8 + 255) / 256, 256, 0, stream>>>(
        row, col, ea, dinv, rowstart, rank, ecv, x, xb0);

    int blocks = (NN + 3) / 4;  // wave per row, 4 rows per 256-thread block
    k_spmm<<<blocks, 256, 0, stream>>>(rowstart, deg, ecv, xb0, y1, xb1);
    k_spmm<<<blocks, 256, 0, stream>>>(rowstart, deg, ecv, xb1, y2, xb2);
    k_spmm_comb<<<blocks, 256, 0, stream>>>(rowstart, deg, ecv, xb2, x, y1, y2,
                                            gamma, out);
}

// Round 3
// 237.432 us; speedup vs baseline: 1.1418x; 1.0008x over previous
//
#include <hip/hip_runtime.h>
#include <hip/hip_fp16.h>

#define NN 50000      // nodes (fits in 16 bits: col packed as ushort)
#define NE 800000     // edges
#define DF 64         // features
#define MM 11         // (a,b) tuples
#define OUT_K 4       // DEPTH+1 output planes
#define PAD 16        // row slabs padded to multiple of PAD
#define SLAB_CAP (NE + (PAD - 1) * NN + 64)

typedef unsigned int uivec4 __attribute__((ext_vector_type(4)));

__device__ __forceinline__ float bf2f(unsigned short u) {
    union { unsigned int i; float f; } v; v.i = ((unsigned int)u) << 16; return v.f;
}
__device__ __forceinline__ unsigned short f2bf(float f) {
    union { float f; unsigned int i; } v; v.f = f;
    unsigned int u = v.i + 0x7FFFu + ((v.i >> 16) & 1u);
    return (unsigned short)(u >> 16);
}

// ---------------- CSR build ----------------

// deg AND per-edge rank within its row (the atomic's old value — free sort key)
__global__ void k_deg(const int* __restrict__ row, int* __restrict__ deg,
                      unsigned short* __restrict__ rank) {
    int e = blockIdx.x * blockDim.x + threadIdx.x;
    if (e < NE) {
        int r = row[e];
        rank[e] = (unsigned short)atomicAdd(&deg[r], 1);
    }
}

// slab alloc: 1024-thread blocks, two-level (wave shfl + LDS) scan,
// ONE atomic per block (49 total). gamma parallelized over m on wave 0 of block 0.
__global__ __launch_bounds__(1024) void k_alloc(
        const int* __restrict__ deg, int* __restrict__ counter,
        int* __restrict__ rowstart, float* __restrict__ dinv,
        const float* __restrict__ alphas, const float* __restrict__ w,
        const float* __restrict__ a_arr, const float* __restrict__ b_arr,
        float* __restrict__ gamma) {
    __shared__ int wtot[16];
    __shared__ int blockbase;
    int i = blockIdx.x * 1024 + threadIdx.x;
    int wave = threadIdx.x >> 6;
    int lane = threadIdx.x & 63;

    int d = (i < NN) ? deg[i] : 0;
    int dp = (d + PAD - 1) & ~(PAD - 1);
    int v = dp;
    #pragma unroll
    for (int off = 1; off < 64; off <<= 1) {
        int t = __shfl_up(v, off, 64);
        if (lane >= off) v += t;
    }
    if (lane == 63) wtot[wave] = v;
    __syncthreads();
    if (wave == 0) {
        int t = (lane < 16) ? wtot[lane] : 0;
        #pragma unroll
        for (int off = 1; off < 16; off <<= 1) {
            int u = __shfl_up(t, off, 64);
            if (lane >= off) t += u;
        }
        if (lane == 15) blockbase = atomicAdd(counter, t);  // block total
        if (lane < 16) wtot[lane] = t;                      // inclusive scan
    }
    __syncthreads();
    int base = blockbase + (wave ? wtot[wave - 1] : 0);
    if (i < NN) {
        rowstart[i] = base + v - dp;
        dinv[i] = 1.0f / sqrtf((float)(d == 0 ? 1 : d));
    }

    // gamma[k][j] = sum_m w_m c_{k,m,j}: one m per lane, shuffle-reduce.
    if (blockIdx.x == 0 && wave == 0) {
        float g[OUT_K][OUT_K];
        #pragma unroll
        for (int k = 0; k < OUT_K; ++k)
            #pragma unroll
            for (int j = 0; j < OUT_K; ++j) g[k][j] = 0.f;
        if (lane < MM) {
            int m = lane;
            float a = a_arr[m], b = b_arr[m], wm = w[m];
            float c[OUT_K][OUT_K];
            #pragma unroll
            for (int k = 0; k < OUT_K; ++k)
                #pragma unroll
                for (int j = 0; j < OUT_K; ++j) c[k][j] = 0.f;
            c[0][0] = 1.f;
            float al0 = alphas[m];
            c[1][0] = al0 * 0.5f * (a - b);        // l=-1, r=1
            c[1][1] = al0 * 0.5f * (a + b + 2.f);
            #pragma unroll
            for (int L = 2; L <= 3; ++L) {
                float Lf = (float)L;
                float alL = alphas[(L - 1) * MM + m];
                float alm = alphas[(L - 2) * MM + m];
                float ab = a + b;
                float t2L = 2.f * Lf + ab;
                float coef_l = 2.f * Lf * (Lf + ab) * (t2L - 2.f);
                float inv = 1.f / coef_l;
                float t1 = alL * ((t2L - 1.f) * t2L * (t2L - 2.f)) * inv;
                float t2 = alL * ((t2L - 1.f) * (a * a - b * b)) * inv;
                float t3 = alL * alm * (2.f * (Lf - 1.f + a) * (Lf - 1.f + b) * t2L) * inv;
                #pragma unroll
                for (int j = 0; j < OUT_K; ++j) {
                    float ps = (j > 0) ? c[L - 1][j - 1] : 0.f;
                    c[L][j] = t1 * ps - t2 * c[L - 1][j] - t3 * c[L - 2][j];
                }
            }
            #pragma unroll
            for (int k = 0; k < OUT_K; ++k)
                #pragma unroll
                for (int j = 0; j < OUT_K; ++j) g[k][j] = wm * c[k][j];
        }
        #pragma unroll
        for (int k = 0; k < OUT_K; ++k)
            #pragma unroll
            for (int j = 0; j < OUT_K; ++j) {
                float s = g[k][j];
                #pragma unroll
                for (int off = 32; off >= 1; off >>= 1) s += __shfl_down(s, off, 64);
                if (lane == 0) gamma[k * OUT_K + j] = s;
            }
    }
}

// fill (atomic-free: pos = rowstart + precomputed rank) + vectorized bf16 cast of x.
// Edge weight stores only ea*dinv[col]; dinv[row] is row-constant, applied in SpMM.
__global__ void k_fill_cast(const int* __restrict__ row, const int* __restrict__ col,
                            const float* __restrict__ ea, const float* __restrict__ dinv,
                            const int* __restrict__ rowstart,
                            const unsigned short* __restrict__ rank,
                            unsigned int* __restrict__ ecv,
                            const float* __restrict__ x, unsigned short* __restrict__ xb) {
    int t = blockIdx.x * blockDim.x + threadIdx.x;
    if (t < NE) {
        int r = row[t], c = col[t];
        int pos = rowstart[r] + (int)rank[t];
        float v = ea[t] * dinv[c];
        unsigned short hb = __half_as_ushort(__float2half(v));
        ecv[pos] = (unsigned int)(unsigned short)c | ((unsigned int)hb << 16);
    } else {
        int j = t - NE;
        if (j < (NN * DF) / 8) {
            const float4* xf = (const float4*)x;
            float4 f0 = xf[2 * j];
            float4 f1 = xf[2 * j + 1];
            uint4 o;
            o.x = (unsigned int)f2bf(f0.x) | ((unsigned int)f2bf(f0.y) << 16);
            o.y = (unsigned int)f2bf(f0.z) | ((unsigned int)f2bf(f0.w) << 16);
            o.z = (unsigned int)f2bf(f1.x) | ((unsigned int)f2bf(f1.y) << 16);
            o.w = (unsigned int)f2bf(f1.z) | ((unsigned int)f2bf(f1.w) << 16);
            ((uint4*)xb)[j] = o;
        }
    }
}

// ---------------- SpMM: wave per row, lane = feature, PAD-wide batches, no tail ----
// ecv records are wave-uniform: load as 4x dwordx4 nontemporal (keep L2 for xb gathers).
__device__ __forceinline__ float spmm_row(const unsigned int* __restrict__ ecv,
                                          int s, int n,
                                          const unsigned short* __restrict__ xin,
                                          int lane) {
    float acc = 0.f;
    for (int i = s; i < s + n; i += PAD) {
        const uivec4* p = (const uivec4*)(ecv + i);
        uivec4 q0 = __builtin_nontemporal_load(p);
        uivec4 q1 = __builtin_nontemporal_load(p + 1);
        uivec4 q2 = __builtin_nontemporal_load(p + 2);
        uivec4 q3 = __builtin_nontemporal_load(p + 3);
        unsigned int rec[PAD] = {q0.x, q0.y, q0.z, q0.w, q1.x, q1.y, q1.z, q1.w,
                                 q2.x, q2.y, q2.z, q2.w, q3.x, q3.y, q3.z, q3.w};
        unsigned short g[PAD];
        float vv[PAD];
        #pragma unroll
        for (int j = 0; j < PAD; ++j) {
            int c = (int)(rec[j] & 0xFFFFu);
            vv[j] = __half2float(__ushort_as_half((unsigned short)(rec[j] >> 16)));
            g[j] = xin[c * DF + lane];
        }
        #pragma unroll
        for (int j = 0; j < PAD; ++j) acc += vv[j] * bf2f(g[j]);
    }
    return acc;
}

__global__ __launch_bounds__(256) void k_spmm(
    const int* __restrict__ rowstart, const int* __restrict__ deg,
    const float* __restrict__ dinv,
    const unsigned int* __restrict__ ecv, const unsigned short* __restrict__ xin,
    unsigned short* __restrict__ bout) {
    int r = (blockIdx.x * blockDim.x + threadIdx.x) >> 6;
    int lane = threadIdx.x & 63;
    if (r >= NN) return;
    int s = rowstart[r];
    int n = (deg[r] + PAD - 1) & ~(PAD - 1);
    float acc = spmm_row(ecv, s, n, xin, lane) * dinv[r];
    bout[r * DF + lane] = f2bf(acc);
}

// third SpMM with the output combine fused (y3 never hits memory);
// v1/v2 read back from the bf16 copies (f32 y1/y2 eliminated entirely).
__global__ __launch_bounds__(256) void k_spmm_comb(
    const int* __restrict__ rowstart, const int* __restrict__ deg,
    const float* __restrict__ dinv,
    const unsigned int* __restrict__ ecv, const unsigned short* __restrict__ xin,
    const float* __restrict__ x, const unsigned short* __restrict__ xb1,
    const unsigned short* __restrict__ xb2, const float* __restrict__ gamma,
    float* __restrict__ out) {
    int r = (blockIdx.x * blockDim.x + threadIdx.x) >> 6;
    int lane = threadIdx.x & 63;
    if (r >= NN) return;
    int s = rowstart[r];
    int n = (deg[r] + PAD - 1) & ~(PAD - 1);
    float v3 = spmm_row(ecv, s, n, xin, lane) * dinv[r];
    int i = r * DF + lane;
    float v0 = x[i];
    float v1 = bf2f(xb1[i]);
    float v2 = bf2f(xb2[i]);
    float gm[OUT_K * OUT_K];
    #pragma unroll
    for (int t = 0; t < OUT_K * OUT_K; ++t) gm[t] = gamma[t];
    #pragma unroll
    for (int k = 0; k < OUT_K; ++k) {
        float o = gm[k * OUT_K + 0] * v0 + gm[k * OUT_K + 1] * v1 +
                  gm[k * OUT_K + 2] * v2 + gm[k * OUT_K + 3] * v3;
        out[(r * OUT_K + k) * DF + lane] = o;
    }
}

// ---------------- launch ----------------

extern "C" void kernel_launch(void* const* d_in, const int* in_sizes, int n_in,
                              void* d_out, int out_size, void* d_ws, size_t ws_size,
                              hipStream_t stream) {
    const float* x      = (const float*)d_in[0];
    const int*   ei     = (const int*)d_in[1];
    const float* ea     = (const float*)d_in[2];
    const float* alphas = (const float*)d_in[3];
    const float* w      = (const float*)d_in[4];
    const float* a_arr  = (const float*)d_in[5];
    const float* b_arr  = (const float*)d_in[6];
    float* out = (float*)d_out;
    const int* row = ei;
    const int* col = ei + NE;

    char* ws = (char*)d_ws;
    size_t off = 0;
    auto alloc = [&](size_t bytes) {
        void* p = ws + off;
        off = (off + bytes + 255) & ~(size_t)255;
        return p;
    };
    // deg/counter then ecv are contiguous so ONE memset zeroes all
    // (ecv pad slots must be 0: col=0, fp16 val=0).
    int* deg      = (int*)alloc((size_t)(NN + 1) * sizeof(int));
    int* counter  = deg + NN;
    unsigned int* ecv = (unsigned int*)alloc((size_t)SLAB_CAP * sizeof(unsigned int));
    size_t zero_end = off;
    int* rowstart = (int*)alloc((size_t)NN * sizeof(int));
    float* dinv   = (float*)alloc((size_t)NN * sizeof(float));
    unsigned short* rank = (unsigned short*)alloc((size_t)NE * sizeof(unsigned short));
    unsigned short* xb0 = (unsigned short*)alloc((size_t)NN * DF * sizeof(unsigned short));
    unsigned short* xb1 = (unsigned short*)alloc((size_t)NN * DF * sizeof(unsigned short));
    unsigned short* xb2 = (unsigned short*)alloc((size_t)NN * DF * sizeof(unsigned short));
    float* gamma = (float*)alloc((size_t)OUT_K * OUT_K * sizeof(float));

    (void)hipMemsetAsync(deg, 0, zero_end, stream);

    k_deg<<<(NE + 255) / 256, 256, 0, stream>>>(row, deg, rank);
    k_alloc<<<(NN + 1023) / 1024, 1024, 0, stream>>>(deg, counter, rowstart, dinv,
                                                     alphas, w, a_arr, b_arr, gamma);
    k_fill_cast<<<(NE + (NN * DF) / 8 + 255) / 256, 256, 0, stream>>>(
        row, col, ea, dinv, rowstart, rank, ecv, x, xb0);

    int blocks = (NN + 3) / 4;  // wave per row, 4 rows per 256-thread block
    k_spmm<<<blocks, 256, 0, stream>>>(rowstart, deg, dinv, ecv, xb0, xb1);
    k_spmm<<<blocks, 256, 0, stream>>>(rowstart, deg, dinv, ecv, xb1, xb2);
    k_spmm_comb<<<blocks, 256, 0, stream>>>(rowstart, deg, dinv, ecv, xb2, x, xb1, xb2,
                                            gamma, out);
}